// Round 6
// baseline (237.353 us; speedup 1.0000x reference)
//
#include <hip/hip_runtime.h>
#include <hip/hip_fp16.h>
#include <math.h>

#define S 256
#define A 180
#define B 4
#define NROWS 131          // staged rows per half: 130 data + overlap/pad
#define PMAX 306           // max row stride in halves; NROWS*PMAX*2 = 80,172 B

// Single fused kernel. Block (a,b), 1024 threads = (j, i-quarter).
// For each half h: stage rows [h*126, h*126+131) of the circle-masked fp16
// image into LDS with per-angle row stride P (bank-conflict avoidance), then
// integrate the ray taps whose floor(py) falls in that half (i in a closed-form
// interval since py is monotone in i). Rim taps (d > 126.5) handled in separate
// loops with per-corner clamps; interior loop has no bounds logic.
__global__ __launch_bounds__(1024, 8)
void radon_fused_kernel(const float* __restrict__ img, float* __restrict__ out) {
    __shared__ __half lds[NROWS * PMAX];   // 80,172 B -> 2 blocks/CU

    const int a = blockIdx.x;
    const int b = blockIdx.y;
    const int tid = threadIdx.x;
    const int j = tid & 255;
    const int iq = tid >> 8;

    float ang = (float)a * (float)(M_PI / 179.0);
    float sn, cs;
    sincosf(ang, &sn, &cs);

    // ---- per-angle stride P: lane addr stride = P*cs - sn halves; pick P so
    // the dword stride is far from even integers (conflict-free is odd/fractional)
    int P = 258;
    {
        float best = 1e9f;
        for (int cand = 258; cand <= PMAX; cand += 2) {
            float sd = 0.5f * fabsf((float)cand * cs - sn);   // dwords/lane
            float m = sd - 2.0f * floorf(sd * 0.5f);          // mod 2
            float score = fabsf(m - 1.0f);                    // 0 = odd = free
            if (score < best) { best = score; P = cand; }
        }
    }
    const int Ph = P >> 1;
    const float Pf = (float)P;

    const float ry = (float)j - 127.5f;
    const float bx = fmaf(-sn, ry, 127.5f);
    const float by = fmaf(cs, ry, 127.5f);
    const float ry2 = ry * ry;

    // disk trim: taps beyond d^2 > 16934 (~130.13^2) are provably zero
    float hd = sqrtf(16934.0f - ry2);
    int qlo = max(max((int)ceilf(127.5f - hd), iq * 64), 0);
    int qhi = min(min((int)(127.5f + hd) + 1, iq * 64 + 64), S);

    // interior (no-bounds) region: d^2 <= 126.5^2
    float hf2 = 16002.25f - ry2;
    int flo_i = 1000, fhi_i = 1000;
    if (hf2 > 0.0f) {
        float hfv = sqrtf(hf2);
        flo_i = (int)ceilf(127.5f - hfv);
        fhi_i = (int)(127.5f + hfv) + 1;
    }

    // half split: py(i) = by + sn*(i-127.5) < 128  <=>  i < isplit
    int isplit;
    if (sn > 1e-6f) {
        float t = (128.0f - by) / sn + 127.5f;
        isplit = min(max((int)ceilf(t), 0), 256);
    } else {
        isplit = (by < 128.0f) ? 256 : 0;
    }

    const float2* __restrict__ src2 = (const float2*)(img + (size_t)b * (S * S));
    float acc = 0.0f;

    for (int hh = 0; hh < 2; ++hh) {
        const int ybase = hh * 126;           // h0 rows 0..130, h1 rows 126..256
        __syncthreads();                      // protect previous half's reads

        // ---- stage: circle mask + fp32->fp16, row stride Ph dwords ----
        uint* l32 = (uint*)lds;
#pragma unroll
        for (int it = 0; it < 17; ++it) {
            int idx = it * 1024 + tid;
            if (idx < NROWS * 128) {
                int yl = idx >> 7;
                int xd = idx & 127;
                int g = ybase + yl;
                uint val = 0u;
                if (g < 256) {
                    float2 v = src2[g * 128 + xd];
                    int dy = g - 128;
                    int dy2 = dy * dy;
                    int dx0 = 2 * xd - 128;
                    int dx1 = dx0 + 1;
                    float f0 = (dx0 * dx0 + dy2 <= 16384) ? v.x : 0.0f;
                    float f1 = (dx1 * dx1 + dy2 <= 16384) ? v.y : 0.0f;
                    uint lo = (uint)__half_as_ushort(__float2half(f0));
                    uint hi = (uint)__half_as_ushort(__float2half(f1));
                    val = lo | (hi << 16);
                }
                l32[yl * Ph + xd] = val;
            }
        }
        if (tid < NROWS) l32[tid * Ph + 128] = 0u;  // zero pad col (halves 256,257)
        __syncthreads();

        // ---- integrate this half's i-interval ----
        int ilo = max(qlo, hh ? isplit : 0);
        int ihi = min(qhi, hh ? 256 : isplit);
        if (ilo < ihi) {
            int fl = min(max(flo_i, ilo), ihi);
            int fh = min(max(fhi_i, fl), ihi);

            // rim loops (per-corner validity + clamps), ~5% of taps
            for (int pass = 0; pass < 2; ++pass) {
                int rlo = pass ? fh : ilo;
                int rhi = pass ? ihi : fl;
                for (int i = rlo; i < rhi; ++i) {
                    float rx = (float)i - 127.5f;
                    float px = fmaf(cs, rx, bx);
                    float pyg = fmaf(sn, rx, by);
                    float x0f = floorf(px);
                    float y0f = floorf(pyg);
                    float wx = px - x0f;
                    float wy = pyg - y0f;
                    int x0 = (int)x0f;
                    int y0 = (int)y0f;
                    int y0l = y0 - ybase;
                    bool vx0 = ((unsigned)x0 < 256u);
                    bool vx1 = ((unsigned)(x0 + 1) < 256u);
                    bool vy0 = ((unsigned)y0 < 256u);
                    bool vy1 = ((unsigned)(y0 + 1) < 256u);
                    float ux = 1.0f - wx, uy = 1.0f - wy;
                    float w00 = (vx0 && vy0) ? ux * uy : 0.0f;
                    float w10 = (vx1 && vy0) ? wx * uy : 0.0f;
                    float w01 = (vx0 && vy1) ? ux * wy : 0.0f;
                    float w11 = (vx1 && vy1) ? wx * wy : 0.0f;
                    int x0r = min(max(x0, 0), 255);
                    int x1r = min(max(x0 + 1, 0), 256);
                    int y0r = min(max(y0l, 0), 129);
                    int y1r = min(max(y0l + 1, 0), 130);
                    float v00 = __half2float(lds[y0r * P + x0r]);
                    float v10 = __half2float(lds[y0r * P + x1r]);
                    float v01 = __half2float(lds[y1r * P + x0r]);
                    float v11 = __half2float(lds[y1r * P + x1r]);
                    acc = fmaf(w00, v00, fmaf(w10, v10, fmaf(w01, v01, fmaf(w11, v11, acc))));
                }
            }

            // fast interior loop: all corners in-bounds, local coords
            float px = fmaf(cs, (float)fl - 127.5f, bx);
            float py = fmaf(sn, (float)fl - 127.5f, by - (float)ybase);
#pragma unroll 4
            for (int i = fl; i < fh; ++i) {
                float x0f = floorf(px);
                float y0f = floorf(py);
                float wx = px - x0f;
                float wy = py - y0f;
                int addr = (int)fmaf(y0f, Pf, x0f);   // exact: < 2^24
                const __half* p0 = &lds[addr];
                float v00 = __half2float(p0[0]);
                float v10 = __half2float(p0[1]);
                float v01 = __half2float(p0[P]);
                float v11 = __half2float(p0[P + 1]);
                float r0 = fmaf(wx, v10 - v00, v00);
                float r1 = fmaf(wx, v11 - v01, v01);
                acc = fmaf(wy, r1 - r0, acc + r0);
                px += cs;
                py += sn;
            }
        }
    }

    // ---- reduce 4 i-quarters per j ----
    __syncthreads();
    float* red = (float*)lds;
    red[tid] = acc;
    __syncthreads();
    if (iq == 0) {
        out[((size_t)b * A + a) * S + j] = red[j] + red[j + 256] + red[j + 512] + red[j + 768];
    }
}

extern "C" void kernel_launch(void* const* d_in, const int* in_sizes, int n_in,
                              void* d_out, int out_size, void* d_ws, size_t ws_size,
                              hipStream_t stream) {
    const float* x = (const float*)d_in[0];
    float* out = (float*)d_out;
    radon_fused_kernel<<<dim3(A, B), dim3(1024), 0, stream>>>(x, out);
}

// Round 7
// 200.879 us; speedup vs baseline: 1.1816x; 1.1816x over previous
//
#include <hip/hip_runtime.h>
#include <hip/hip_fp16.h>
#include <math.h>

#define S 256
#define A 180
#define B 4
#define PMAX 316           // max row stride (halves); 257*316*2 = 162,424 B LDS
#define NROWS 257          // 256 image rows + zero pad row

// One block per (angle, batch), 1024 threads = (j, i-quarter). Stage the
// circle-masked fp16 image into LDS with a per-angle row stride P chosen so the
// wave's lane address stride is ~odd in dwords (bank-conflict avoidance), then
// every thread integrates its ray quarter in ONE phase (no mid-kernel barriers
// -- R6's half-split idled half the waves per phase). Rim taps (d > 126.5) run
// in separate loops with per-corner clamps; the interior loop has no bounds
// logic. Taps beyond d^2 > 16934 (~130.13^2) are provably zero (every in-bounds
// corner is >128 from center -> masked to 0; OOB corners carry zero weight).
__global__ __launch_bounds__(1024, 1)
void radon_fused_kernel(const float* __restrict__ img, float* __restrict__ out) {
    __shared__ __half lds[NROWS * PMAX];

    const int a = blockIdx.x;
    const int b = blockIdx.y;
    const int tid = threadIdx.x;
    const int j = tid & 255;
    const int iq = tid >> 8;

    float ang = (float)a * (float)(M_PI / 179.0);
    float sn, cs;
    sincosf(ang, &sn, &cs);

    // per-angle stride: lane stride = P*cs - sn halves; want dword stride ~odd
    int P = 258;
    {
        float best = 1e9f;
        for (int cand = 258; cand <= PMAX; cand += 2) {
            float sd = 0.5f * fabsf((float)cand * cs - sn);   // dwords/lane
            float m = sd - 2.0f * floorf(sd * 0.5f);          // mod 2
            float score = fabsf(m - 1.0f);                    // 0 = odd = free
            if (score < best) { best = score; P = cand; }
        }
    }
    const int Ph = P >> 1;
    const float Pf = (float)P;

    // ---- stage: circle mask (dx^2+dy^2 <= 128^2 == sqrt<=128) + fp32->fp16 ----
    const float2* __restrict__ src2 = (const float2*)(img + (size_t)b * (S * S));
    uint* l32 = (uint*)lds;
#pragma unroll
    for (int it = 0; it < 32; ++it) {
        int idx = it * 1024 + tid;      // = yl*128 + xd, rows 0..255
        int yl = idx >> 7;
        int xd = idx & 127;
        float2 v = src2[idx];
        int dy = yl - 128;
        int dy2 = dy * dy;
        int dx0 = 2 * xd - 128;
        int dx1 = dx0 + 1;
        float f0 = (dx0 * dx0 + dy2 <= 16384) ? v.x : 0.0f;
        float f1 = (dx1 * dx1 + dy2 <= 16384) ? v.y : 0.0f;
        uint lo = (uint)__half_as_ushort(__float2half(f0));
        uint hi = (uint)__half_as_ushort(__float2half(f1));
        l32[yl * Ph + xd] = lo | (hi << 16);
    }
    // zero pad col (halves 256/257, rows 0..256) and pad row 256 (dwords 0..128)
    if (tid < 257) {
        l32[tid * Ph + 128] = 0u;
    } else if (tid < 257 + 129) {
        l32[256 * Ph + (tid - 257)] = 0u;
    }
    __syncthreads();

    // ---- ray setup ----
    const float ry = (float)j - 127.5f;
    const float bx = fmaf(-sn, ry, 127.5f);
    const float by = fmaf(cs, ry, 127.5f);
    const float ry2 = ry * ry;

    float hd = sqrtf(16934.0f - ry2);
    int ilo = max(max((int)ceilf(127.5f - hd), iq * 64), 0);
    int ihi = min(min((int)(127.5f + hd) + 1, iq * 64 + 64), S);

    // interior (no-bounds) region: d^2 <= 126.5^2
    float hf2 = 16002.25f - ry2;
    int fl, fh;
    if (hf2 > 0.0f) {
        float hfv = sqrtf(hf2);
        fl = min(max((int)ceilf(127.5f - hfv), ilo), ihi);
        fh = min(max((int)(127.5f + hfv) + 1, fl), ihi);
    } else {
        fl = ilo; fh = ilo;   // j=0 / j=255: all rim
    }

    float acc = 0.0f;

    // ---- rim loops: per-corner validity + independent clamps ----
    for (int pass = 0; pass < 2; ++pass) {
        int rlo = pass ? fh : ilo;
        int rhi = pass ? ihi : fl;
        for (int i = rlo; i < rhi; ++i) {
            float rx = (float)i - 127.5f;
            float px = fmaf(cs, rx, bx);
            float py = fmaf(sn, rx, by);
            float x0f = floorf(px);
            float y0f = floorf(py);
            float wx = px - x0f;
            float wy = py - y0f;
            int x0 = (int)x0f;
            int y0 = (int)y0f;
            bool vx0 = ((unsigned)x0 < 256u);
            bool vx1 = ((unsigned)(x0 + 1) < 256u);
            bool vy0 = ((unsigned)y0 < 256u);
            bool vy1 = ((unsigned)(y0 + 1) < 256u);
            float ux = 1.0f - wx, uy = 1.0f - wy;
            float w00 = (vx0 && vy0) ? ux * uy : 0.0f;
            float w10 = (vx1 && vy0) ? wx * uy : 0.0f;
            float w01 = (vx0 && vy1) ? ux * wy : 0.0f;
            float w11 = (vx1 && vy1) ? wx * wy : 0.0f;
            int x0r = min(max(x0, 0), 255);
            int x1r = min(max(x0 + 1, 0), 256);    // col 256 = zeroed pad
            int y0r = min(max(y0, 0), 255);
            int y1r = min(max(y0 + 1, 0), 256);    // row 256 = zeroed pad
            float v00 = __half2float(lds[y0r * P + x0r]);
            float v10 = __half2float(lds[y0r * P + x1r]);
            float v01 = __half2float(lds[y1r * P + x0r]);
            float v11 = __half2float(lds[y1r * P + x1r]);
            acc = fmaf(w00, v00, fmaf(w10, v10, fmaf(w01, v01, fmaf(w11, v11, acc))));
        }
    }

    // ---- fast interior loop: all corners in-bounds, incremental stepping ----
    {
        float px = fmaf(cs, (float)fl - 127.5f, bx);
        float py = fmaf(sn, (float)fl - 127.5f, by);
#pragma unroll 4
        for (int i = fl; i < fh; ++i) {
            float x0f = floorf(px);
            float y0f = floorf(py);
            float wx = px - x0f;
            float wy = py - y0f;
            int addr = (int)fmaf(y0f, Pf, x0f);   // exact: < 2^17
            const __half* p0 = &lds[addr];
            float v00 = __half2float(p0[0]);
            float v10 = __half2float(p0[1]);
            float v01 = __half2float(p0[P]);
            float v11 = __half2float(p0[P + 1]);
            float r0 = fmaf(wx, v10 - v00, v00);
            float r1 = fmaf(wx, v11 - v01, v01);
            acc = fmaf(wy, r1 - r0, acc + r0);
            px += cs;
            py += sn;
        }
    }

    // ---- reduce 4 i-quarters per j ----
    __syncthreads();
    float* red = (float*)lds;
    red[tid] = acc;
    __syncthreads();
    if (iq == 0) {
        out[((size_t)b * A + a) * S + j] = red[j] + red[j + 256] + red[j + 512] + red[j + 768];
    }
}

extern "C" void kernel_launch(void* const* d_in, const int* in_sizes, int n_in,
                              void* d_out, int out_size, void* d_ws, size_t ws_size,
                              hipStream_t stream) {
    const float* x = (const float*)d_in[0];
    float* out = (float*)d_out;
    radon_fused_kernel<<<dim3(A, B), dim3(1024), 0, stream>>>(x, out);
}

// Round 8
// 118.125 us; speedup vs baseline: 2.0093x; 1.7006x over previous
//
#include <hip/hip_runtime.h>
#include <hip/hip_fp16.h>
#include <math.h>

#define S 256
#define A 180
#define B 4
#define PMAX 316           // max row stride in halves; 257*316*2 = 162,424 B LDS
#define NROWS 257          // 256 image rows + 1 zero pad row

// Kernel 1: inscribed-circle mask (dx^2+dy^2 <= 128^2 == sqrt<=128) + fp32->fp16.
__global__ void radon_mask_f16(const float* __restrict__ in, __half* __restrict__ out) {
    int idx = blockIdx.x * 256 + threadIdx.x;    // 0 .. B*S*S-1
    int p = idx & (S * S - 1);
    int y = p >> 8;
    int x = p & 255;
    int dx = x - 128, dy = y - 128;
    float v = in[idx];
    v = (dx * dx + dy * dy <= 16384) ? v : 0.0f;
    out[idx] = __float2half(v);
}

// Kernel 2: EXACT R5 structure (90.5 us proven) + ONE change: per-angle runtime
// row stride P (bank-conflict avoidance; picked so the wave's lane address
// stride is ~odd in dwords). One block per (angle,batch), 1024 threads =
// (j, i-quarter). Single unified tap loop with in-loop rim branch (R6/R7's
// split loops regressed). Taps beyond d^2 > 16934 (~130.13^2) are provably
// zero; interior d <= 126.5 needs no bounds logic; rim clamps each corner
// index independently.
__global__ __launch_bounds__(1024, 1) void radon_lds_kernel(const __half* __restrict__ img,
                                                            float* __restrict__ out) {
    __shared__ __half lds[NROWS * PMAX];         // 162,424 B

    const int a = blockIdx.x;   // angle
    const int b = blockIdx.y;   // batch
    const int tid = threadIdx.x;

    float ang = (float)a * (float)(M_PI / 179.0);
    float sn, cs;
    sincosf(ang, &sn, &cs);

    // per-angle stride: lane half-stride = P*cs - sn; want dword stride ~odd
    int P = 258;
    {
        float best = 1e9f;
        for (int cand = 258; cand <= PMAX; cand += 2) {
            float sd = 0.5f * fabsf((float)cand * cs - sn);   // dwords/lane
            float m = sd - 2.0f * floorf(sd * 0.5f);          // mod 2
            float score = fabsf(m - 1.0f);                    // 0 = odd = free
            if (score < best) { best = score; P = cand; }
        }
    }
    const int Ph = P >> 1;

    // ---- stage image (65536 halves = 32768 dwords), coalesced ----
    const uint* __restrict__ src = (const uint*)(img + (size_t)b * (S * S));
    uint* l32 = (uint*)lds;
#pragma unroll
    for (int k = 0; k < 32; ++k) {
        int p = k * 1024 + tid;
        int y = p >> 7;            // 128 dwords per source row
        int xp = p & 127;
        l32[y * Ph + xp] = src[p];
    }
    // zero pad cols 256/257 of rows 0..255 and all of pad row 256 (dwords 0..128)
    if (tid < 256) {
        l32[tid * Ph + 128] = 0u;
    } else if (tid < 256 + 129) {
        l32[256 * Ph + (tid - 256)] = 0u;
    }
    __syncthreads();

    const int j = tid & 255;
    const int iq = tid >> 8;

    const float ry = (float)j - 127.5f;
    const float bx = fmaf(-sn, ry, 127.5f);
    const float by = fmaf(cs, ry, 127.5f);
    const float ry2 = ry * ry;

    // disk trim: keep i with rx^2 + ry^2 <= 16934 (~130.13^2 > provable 130.122)
    float h = sqrtf(16934.0f - ry2);
    int ilo = (int)ceilf(127.5f - h);
    int ihi = (int)floorf(127.5f + h) + 1;
    ilo = max(ilo, iq * 64);
    ihi = min(ihi, iq * 64 + 64);
    ilo = max(ilo, 0);
    ihi = min(ihi, S);

    const float FAST2 = 126.5f * 126.5f;
    float acc = 0.0f;

#pragma unroll 4
    for (int i = ilo; i < ihi; ++i) {
        float rx = (float)i - 127.5f;
        float px = fmaf(cs, rx, bx);
        float py = fmaf(sn, rx, by);

        float x0f = floorf(px);
        float y0f = floorf(py);
        float wx = px - x0f;
        float wy = py - y0f;
        int x0 = (int)x0f;
        int y0 = (int)y0f;
        float ux = 1.0f - wx;
        float uy = 1.0f - wy;
        float w00 = ux * uy;
        float w10 = wx * uy;
        float w01 = ux * wy;
        float w11 = wx * wy;

        float v00, v10, v01, v11;
        float d2 = fmaf(rx, rx, ry2);
        if (d2 <= FAST2) {
            // interior: px,py in [1,254] -> all corners in-bounds
            const __half* p0 = &lds[y0 * P + x0];
            v00 = __half2float(p0[0]);
            v10 = __half2float(p0[1]);
            v01 = __half2float(p0[P]);
            v11 = __half2float(p0[P + 1]);
        } else {
            // rim: zero weights of OOB corners, clamp each index independently
            bool vx0 = ((unsigned)x0 < 256u);
            bool vx1 = ((unsigned)(x0 + 1) < 256u);
            bool vy0 = ((unsigned)y0 < 256u);
            bool vy1 = ((unsigned)(y0 + 1) < 256u);
            w00 = (vx0 && vy0) ? w00 : 0.0f;
            w10 = (vx1 && vy0) ? w10 : 0.0f;
            w01 = (vx0 && vy1) ? w01 : 0.0f;
            w11 = (vx1 && vy1) ? w11 : 0.0f;
            int x0r = min(max(x0, 0), 255);
            int x1r = min(max(x0 + 1, 0), 256);    // col 256 = zeroed pad
            int y0r = min(max(y0, 0), 255);
            int y1r = min(max(y0 + 1, 0), 256);    // row 256 = zeroed pad
            v00 = __half2float(lds[y0r * P + x0r]);
            v10 = __half2float(lds[y0r * P + x1r]);
            v01 = __half2float(lds[y1r * P + x0r]);
            v11 = __half2float(lds[y1r * P + x1r]);
        }

        acc = fmaf(w00, v00, fmaf(w10, v10, fmaf(w01, v01, fmaf(w11, v11, acc))));
    }

    // ---- reduce the 4 i-quarters per j (reuse LDS after barrier) ----
    __syncthreads();
    float* red = (float*)lds;
    red[tid] = acc;
    __syncthreads();
    if (iq == 0) {
        float r = red[j] + red[j + 256] + red[j + 512] + red[j + 768];
        out[((size_t)b * A + a) * S + j] = r;
    }
}

extern "C" void kernel_launch(void* const* d_in, const int* in_sizes, int n_in,
                              void* d_out, int out_size, void* d_ws, size_t ws_size,
                              hipStream_t stream) {
    const float* x = (const float*)d_in[0];
    float* out = (float*)d_out;
    __half* masked = (__half*)d_ws;  // B*S*S halves = 512 KiB

    radon_mask_f16<<<dim3((B * S * S) / 256), dim3(256), 0, stream>>>(x, masked);
    radon_lds_kernel<<<dim3(A, B), dim3(1024), 0, stream>>>(masked, out);
}